// Round 7
// baseline (146.324 us; speedup 1.0000x reference)
//
#include <hip/hip_runtime.h>

typedef unsigned short ushort_t;
typedef __attribute__((ext_vector_type(8))) short short8;
typedef __attribute__((ext_vector_type(4))) float f32x4;
typedef __attribute__((ext_vector_type(4))) unsigned short ushort4v;
typedef __attribute__((ext_vector_type(8))) unsigned short ushort8v;

#define S_LEN 2048
#define D_MODEL 1024
#define NH 16
#define NKV 4
#define HD 64

// fp32 -> bf16 round-to-nearest-even
__device__ __forceinline__ ushort_t f2bf(float f) {
    unsigned u = __float_as_uint(f);
    u += 0x7fffu + ((u >> 16) & 1u);
    return (ushort_t)(u >> 16);
}

// async global->LDS, 16B/lane; LDS base wave-uniform, HW scatters lane*16
__device__ __forceinline__ void cp16(void* lds, const void* g) {
    __builtin_amdgcn_global_load_lds(
        (__attribute__((address_space(1))) void*)g,
        (__attribute__((address_space(3))) void*)lds, 16, 0, 0);
}

// ---------------------------------------------------------------------------
// Preprocess: z=0..3 -> weight transpose+cast W[k][n] fp32 -> WT[n][k] bf16;
// z=4 -> x fp32 -> bf16. grid (16,16,5).  (baseline verbatim)
// ---------------------------------------------------------------------------
__global__ __launch_bounds__(256) void prep_kernel(
    const float* __restrict__ x, ushort_t* __restrict__ xb,
    const float* __restrict__ Wq, const float* __restrict__ Wk,
    const float* __restrict__ Wv, const float* __restrict__ Wo,
    ushort_t* __restrict__ WqT, ushort_t* __restrict__ WkT,
    ushort_t* __restrict__ WvT, ushort_t* __restrict__ WoT)
{
    const int t = threadIdx.x;
    if (blockIdx.z == 4) {
        const int b  = blockIdx.y * 16 + blockIdx.x;
        const int i0 = (b * 256 + t) * 4;
        #pragma unroll
        for (int rep = 0; rep < 8; ++rep) {
            const int i = i0 + rep * 262144;   // 8 x 256K covers 2048*1024
            float4 v = *(const float4*)(x + i);
            ushort4v o = { f2bf(v.x), f2bf(v.y), f2bf(v.z), f2bf(v.w) };
            *(ushort4v*)(xb + i) = o;
        }
        return;
    }
    __shared__ ushort_t T[64 * 72];
    const float* W; ushort_t* WT; int N;
    switch (blockIdx.z) {
        case 0:  W = Wq; WT = WqT; N = 1024; break;
        case 1:  W = Wk; WT = WkT; N = 256;  break;
        case 2:  W = Wv; WT = WvT; N = 256;  break;
        default: W = Wo; WT = WoT; N = 1024; break;
    }
    const int n0 = blockIdx.y * 64;
    if (n0 >= N) return;
    const int k0 = blockIdx.x * 64;
    const int kr = t >> 4, nc = (t & 15) * 4;
    #pragma unroll
    for (int p = 0; p < 4; ++p) {
        const int k = kr + p * 16;
        float4 v = *(const float4*)(W + (size_t)(k0 + k) * N + n0 + nc);
        T[(nc + 0) * 72 + k] = f2bf(v.x);
        T[(nc + 1) * 72 + k] = f2bf(v.y);
        T[(nc + 2) * 72 + k] = f2bf(v.z);
        T[(nc + 3) * 72 + k] = f2bf(v.w);
    }
    __syncthreads();
    const int n = t >> 2, seg = (t & 3) * 16;
    ushort8v a = *(ushort8v*)&T[n * 72 + seg];
    ushort8v b = *(ushort8v*)&T[n * 72 + seg + 8];
    *(ushort8v*)(WT + (size_t)(n0 + n) * 1024 + k0 + seg)     = a;
    *(ushort8v*)(WT + (size_t)(n0 + n) * 1024 + k0 + seg + 8) = b;
}

// ---------------------------------------------------------------------------
// QKV projection (R6 structure kept): 64x64 tile, grid (32,24)=768 balanced,
// 4-deep circular LDS + counted vmcnt + raw s_barrier (T4).
// ---------------------------------------------------------------------------
__global__ __launch_bounds__(256, 2) void gemm_qkv_mfma(
    const ushort_t* __restrict__ xb, const ushort_t* __restrict__ WqT,
    const ushort_t* __restrict__ WkT, const ushort_t* __restrict__ WvT,
    const float* __restrict__ rc, const float* __restrict__ rs,
    ushort_t* __restrict__ Qb, ushort_t* __restrict__ Kb,
    ushort_t* __restrict__ Vtb)
{
    __shared__ ushort_t As[4][64 * 64];    // 32 KB
    __shared__ ushort_t Bs[4][64 * 64];    // 32 KB

    const int t = threadIdx.x;
    const int lane = t & 63, wave = t >> 6;
    const int wr = wave >> 1, wc = wave & 1;
    const int quad = lane >> 4, l15 = lane & 15;
    const int lq = lane >> 3, lr = lane & 7;
    const int swz_st = (lr ^ lq) * 8;
    const int l7 = l15 & 7;
    const int fsw0 = (quad ^ l7) * 8;
    const int fsw1 = ((quad + 4) ^ l7) * 8;

    const int m0 = blockIdx.x * 64;
    const int cy = blockIdx.y;

    const ushort_t* WT; int nloc;
    if (cy < 16)      { WT = WqT; nloc = cy * 64; }
    else if (cy < 20) { WT = WkT; nloc = (cy - 16) * 64; }
    else              { WT = WvT; nloc = (cy - 20) * 64; }

    f32x4 acc[2][2];
    #pragma unroll
    for (int i = 0; i < 2; ++i)
        #pragma unroll
        for (int j = 0; j < 2; ++j) acc[i][j] = (f32x4)0.f;

    auto stage = [&](int buf, int k0) {
        #pragma unroll
        for (int i = 0; i < 2; ++i) {
            const int r = wave * 16 + i * 8 + lq;
            cp16(&As[buf][(wave * 16 + i * 8) * 64],
                 xb + (size_t)(m0 + r) * 1024 + k0 + swz_st);
            cp16(&Bs[buf][(wave * 16 + i * 8) * 64],
                 WT + (size_t)(nloc + r) * 1024 + k0 + swz_st);
        }
    };

    auto compute = [&](int cur) {
        const ushort_t* Ac = &As[cur][0];
        const ushort_t* Bc = &Bs[cur][0];
        #pragma unroll
        for (int h = 0; h < 2; ++h) {
            const int fsw = h ? fsw1 : fsw0;
            short8 av[2], bv[2];
            #pragma unroll
            for (int i = 0; i < 2; ++i)
                av[i] = *(const short8*)&Ac[(wr * 32 + i * 16 + l15) * 64 + fsw];
            #pragma unroll
            for (int j = 0; j < 2; ++j)   // interleaved cols wc*16 + j*32
                bv[j] = *(const short8*)&Bc[(wc * 16 + j * 32 + l15) * 64 + fsw];
            #pragma unroll
            for (int i = 0; i < 2; ++i)
                #pragma unroll
                for (int j = 0; j < 2; ++j)
                    acc[i][j] = __builtin_amdgcn_mfma_f32_16x16x32_bf16(
                        av[i], bv[j], acc[i][j], 0, 0, 0);
        }
    };

    stage(0, 0);
    stage(1, 64);
    stage(2, 128);

    for (int kk = 0; kk < 14; ++kk) {
        asm volatile("s_waitcnt vmcnt(8)" ::: "memory");
        __builtin_amdgcn_s_barrier();
        __builtin_amdgcn_sched_barrier(0);
        if (kk < 13) stage((kk + 3) & 3, (kk + 3) * 64);
        compute(kk & 3);
    }
    asm volatile("s_waitcnt vmcnt(4)" ::: "memory");
    __builtin_amdgcn_s_barrier();
    __builtin_amdgcn_sched_barrier(0);
    compute(2);                      // 14 & 3
    asm volatile("s_waitcnt vmcnt(0)" ::: "memory");
    __builtin_amdgcn_s_barrier();
    __builtin_amdgcn_sched_barrier(0);
    compute(3);                      // 15 & 3

    // epilogue: C/D layout col = l15, row = quad*4+reg (+16i)  [m89]
    if (cy < 20) {
        ushort_t* dst = (cy < 16) ? Qb : Kb;
        const int h = (cy < 16) ? cy : (cy - 16);
        const int d = wc * 16 + l15;
        #pragma unroll
        for (int i = 0; i < 2; ++i) {
            #pragma unroll
            for (int reg = 0; reg < 4; ++reg) {
                const int s = m0 + wr * 32 + i * 16 + quad * 4 + reg;
                const float c  = rc[s * 32 + d];
                const float sn = rs[s * 32 + d];
                const float v1 = acc[i][0][reg];    // x[d]
                const float v2 = acc[i][1][reg];    // x[d+32]
                dst[((size_t)h * S_LEN + s) * HD + d]      = f2bf(v1 * c - v2 * sn);
                dst[((size_t)h * S_LEN + s) * HD + d + 32] = f2bf(v2 * c + v1 * sn);
            }
        }
    } else {
        const int vh = cy - 20;
        #pragma unroll
        for (int i = 0; i < 2; ++i) {
            const int s0 = m0 + wr * 32 + i * 16 + quad * 4;
            #pragma unroll
            for (int j = 0; j < 2; ++j) {
                const int d = wc * 16 + j * 32 + l15;
                ushort4v o = { f2bf(acc[i][j][0]), f2bf(acc[i][j][1]),
                               f2bf(acc[i][j][2]), f2bf(acc[i][j][3]) };
                *(ushort4v*)&Vtb[((size_t)vh * HD + d) * S_LEN + s0] = o;
            }
        }
    }
}

// ---------------------------------------------------------------------------
// MFMA flash attention, ROUND 7: T4 counted-vmcnt pipeline at 64-KV sub-tile
// granularity. 4-deep circular K/V buffers (same 73 KB total as baseline,
// 2 blocks/CU kept). Per step: wait vmcnt(min(rem,2)*4) (each stage64 = 4
// cp16/wave, up to 2 stages in flight), s_barrier + sched_barrier(0), issue
// stage s+3, compute sub-tile s. Buffer: write@s, read@s+3, rewrite@s+7.
// Replaces the per-128-round __syncthreads (= vmcnt(0) full drain of the
// just-issued next-round loads). Compute body unchanged from baseline.
// ---------------------------------------------------------------------------
__global__ __launch_bounds__(256, 2) void attn_mfma(
    const ushort_t* __restrict__ Qb, const ushort_t* __restrict__ Kb,
    const ushort_t* __restrict__ Vtb, ushort_t* __restrict__ attnb)
{
    __shared__ ushort_t Ks[4][64 * 64];   // 32 KB [buf][kv][d] swizzled
    __shared__ ushort_t Vs[4][64 * 64];   // 32 KB [buf][d][kv] swizzled
    __shared__ ushort_t Ps[4][16 * 72];   // 9 KB wave-private P

    const int t = threadIdx.x;
    const int lane = t & 63, wave = t >> 6;
    const int quad = lane >> 4, l15 = lane & 15;
    const int lq = lane >> 3, lr = lane & 7;
    const int swz_st = (lr ^ lq) * 8;
    const int l7 = l15 & 7;
    const int fsw0 = (quad ^ l7) * 8;
    const int fsw1 = ((quad + 4) ^ l7) * 8;

    const int h  = blockIdx.x;
    const int y  = blockIdx.y;
    const int qt = (y < 16) ? y : 47 - y;
    const int q0 = qt * 64;
    const int kvh = h >> 2;
    const int qrow0 = q0 + wave * 16;

    const ushort_t* Qg = Qb + ((size_t)h * S_LEN + qrow0) * HD;
    const ushort_t* Kg = Kb + (size_t)kvh * S_LEN * HD;
    const ushort_t* Vg = Vtb + (size_t)kvh * HD * S_LEN;

    short8 aq0 = *(const short8*)(Qg + (size_t)l15 * HD + quad * 8);
    short8 aq1 = *(const short8*)(Qg + (size_t)l15 * HD + 32 + quad * 8);

    float ps4[4] = {0.f, 0.f, 0.f, 0.f};
    f32x4 Oacc[4];
    #pragma unroll
    for (int jb = 0; jb < 4; ++jb) Oacc[jb] = (f32x4)0.f;

    const int nsub = qt + 1;   // 64-KV sub-tiles (kv0 = s*64 <= q0)

    auto stage64 = [&](int s) {
        const int kv0 = s * 64;
        ushort_t* Kd = &Ks[s & 3][0];
        ushort_t* Vd = &Vs[s & 3][0];
        #pragma unroll
        for (int i = 0; i < 2; ++i) {
            const int rr = wave * 16 + i * 8;
            const int r = rr + lq;
            cp16(&Kd[rr * 64], Kg + (size_t)(kv0 + r) * 64 + swz_st);
            cp16(&Vd[rr * 64], Vg + (size_t)r * 2048 + kv0 + swz_st);
        }
    };

    stage64(0);
    if (nsub > 1) stage64(1);
    if (nsub > 2) stage64(2);

    ushort_t* Pw = &Ps[wave][0];

    for (int s = 0; s < nsub; ++s) {
        const int rem = nsub - 1 - s;     // stages issued after s (uniform)
        if (rem >= 2)      asm volatile("s_waitcnt vmcnt(8)" ::: "memory");
        else if (rem == 1) asm volatile("s_waitcnt vmcnt(4)" ::: "memory");
        else               asm volatile("s_waitcnt vmcnt(0)" ::: "memory");
        __builtin_amdgcn_s_barrier();
        __builtin_amdgcn_sched_barrier(0);
        if (s + 3 < nsub) stage64(s + 3);

        const int kv0 = s * 64;
        const ushort_t* Kc = &Ks[s & 3][0];
        const ushort_t* Vc = &Vs[s & 3][0];

        // S = Q K^T
        f32x4 sv[4];
        #pragma unroll
        for (int jb = 0; jb < 4; ++jb) {
            short8 b0 = *(const short8*)&Kc[(jb * 16 + l15) * 64 + fsw0];
            short8 b1 = *(const short8*)&Kc[(jb * 16 + l15) * 64 + fsw1];
            f32x4 z = (f32x4)0.f;
            z = __builtin_amdgcn_mfma_f32_16x16x32_bf16(aq0, b0, z, 0, 0, 0);
            z = __builtin_amdgcn_mfma_f32_16x16x32_bf16(aq1, b1, z, 0, 0, 0);
            sv[jb] = z;
        }

        // max-free softmax: P = exp(s/8); mask only on the diagonal sub-tile
        const bool diag = (kv0 == q0);
        #pragma unroll
        for (int jb = 0; jb < 4; ++jb) {
            const int col = kv0 + jb * 16 + l15;
            #pragma unroll
            for (int reg = 0; reg < 4; ++reg) {
                float e = __expf(sv[jb][reg] * 0.125f);
                if (diag && col > qrow0 + quad * 4 + reg) e = 0.f;
                sv[jb][reg] = e;
                ps4[reg] += e;
            }
        }

        // P: C-layout -> wave-private LDS -> A-layout frags  [m120]
        #pragma unroll
        for (int jb = 0; jb < 4; ++jb)
            #pragma unroll
            for (int reg = 0; reg < 4; ++reg)
                Pw[(quad * 4 + reg) * 72 + jb * 16 + l15] = f2bf(sv[jb][reg]);
        short8 p0 = *(const short8*)&Pw[l15 * 72 + quad * 8];
        short8 p1 = *(const short8*)&Pw[l15 * 72 + 32 + quad * 8];

        // O += P V
        #pragma unroll
        for (int jb = 0; jb < 4; ++jb) {
            short8 v0 = *(const short8*)&Vc[(jb * 16 + l15) * 64 + fsw0];
            short8 v1 = *(const short8*)&Vc[(jb * 16 + l15) * 64 + fsw1];
            Oacc[jb] = __builtin_amdgcn_mfma_f32_16x16x32_bf16(p0, v0, Oacc[jb], 0, 0, 0);
            Oacc[jb] = __builtin_amdgcn_mfma_f32_16x16x32_bf16(p1, v1, Oacc[jb], 0, 0, 0);
        }
    }

    // final row-sum reduction + normalize + store
    #pragma unroll
    for (int reg = 0; reg < 4; ++reg) {
        float l = ps4[reg];
        l += __shfl_xor(l, 1);
        l += __shfl_xor(l, 2);
        l += __shfl_xor(l, 4);
        l += __shfl_xor(l, 8);
        const float inv = 1.f / l;
        const int s = qrow0 + quad * 4 + reg;
        #pragma unroll
        for (int jb = 0; jb < 4; ++jb)
            attnb[(size_t)s * D_MODEL + h * HD + jb * 16 + l15] =
                f2bf(Oacc[jb][reg] * inv);
    }
}

// ---------------------------------------------------------------------------
// Output projection (R6 structure kept): 64x64 tile, grid (32,16)=512,
// 4-deep circular LDS, counted vmcnt.
// ---------------------------------------------------------------------------
__global__ __launch_bounds__(256, 2) void gemm_out_mfma(
    const ushort_t* __restrict__ Ab, const ushort_t* __restrict__ WoT,
    float* __restrict__ out)
{
    __shared__ ushort_t As[4][64 * 64];    // 32 KB
    __shared__ ushort_t Bs[4][64 * 64];    // 32 KB

    const int t = threadIdx.x;
    const int lane = t & 63, wave = t >> 6;
    const int wr = wave >> 1, wc = wave & 1;
    const int quad = lane >> 4, l15 = lane & 15;
    const int lq = lane >> 3, lr = lane & 7;
    const int swz_st = (lr ^ lq) * 8;
    const int l7 = l15 & 7;
    const int fsw0 = (quad ^ l7) * 8;
    const int fsw1 = ((quad + 4) ^ l7) * 8;

    const int m0 = blockIdx.x * 64;
    const int n0 = blockIdx.y * 64;

    f32x4 acc[2][2];
    #pragma unroll
    for (int i = 0; i < 2; ++i)
        #pragma unroll
        for (int j = 0; j < 2; ++j) acc[i][j] = (f32x4)0.f;

    auto stage = [&](int buf, int k0) {
        #pragma unroll
        for (int i = 0; i < 2; ++i) {
            const int r = wave * 16 + i * 8 + lq;
            cp16(&As[buf][(wave * 16 + i * 8) * 64],
                 Ab + (size_t)(m0 + r) * 1024 + k0 + swz_st);
            cp16(&Bs[buf][(wave * 16 + i * 8) * 64],
                 WoT + (size_t)(n0 + r) * 1024 + k0 + swz_st);
        }
    };

    auto compute = [&](int cur) {
        const ushort_t* Ac = &As[cur][0];
        const ushort_t* Bc = &Bs[cur][0];
        #pragma unroll
        for (int h = 0; h < 2; ++h) {
            const int fsw = h ? fsw1 : fsw0;
            short8 av[2], bv[2];
            #pragma unroll
            for (int i = 0; i < 2; ++i)
                av[i] = *(const short8*)&Ac[(wr * 32 + i * 16 + l15) * 64 + fsw];
            #pragma unroll
            for (int j = 0; j < 2; ++j)
                bv[j] = *(const short8*)&Bc[(wc * 32 + j * 16 + l15) * 64 + fsw];
            #pragma unroll
            for (int i = 0; i < 2; ++i)
                #pragma unroll
                for (int j = 0; j < 2; ++j)
                    acc[i][j] = __builtin_amdgcn_mfma_f32_16x16x32_bf16(
                        av[i], bv[j], acc[i][j], 0, 0, 0);
        }
    };

    stage(0, 0);
    stage(1, 64);
    stage(2, 128);

    for (int kk = 0; kk < 14; ++kk) {
        asm volatile("s_waitcnt vmcnt(8)" ::: "memory");
        __builtin_amdgcn_s_barrier();
        __builtin_amdgcn_sched_barrier(0);
        if (kk < 13) stage((kk + 3) & 3, (kk + 3) * 64);
        compute(kk & 3);
    }
    asm volatile("s_waitcnt vmcnt(4)" ::: "memory");
    __builtin_amdgcn_s_barrier();
    __builtin_amdgcn_sched_barrier(0);
    compute(2);                      // 14 & 3
    asm volatile("s_waitcnt vmcnt(0)" ::: "memory");
    __builtin_amdgcn_s_barrier();
    __builtin_amdgcn_sched_barrier(0);
    compute(3);                      // 15 & 3

    #pragma unroll
    for (int i = 0; i < 2; ++i)
        #pragma unroll
        for (int reg = 0; reg < 4; ++reg) {
            const int s = m0 + wr * 32 + i * 16 + quad * 4 + reg;
            #pragma unroll
            for (int j = 0; j < 2; ++j)
                out[(size_t)s * D_MODEL + n0 + wc * 32 + j * 16 + l15] = acc[i][j][reg];
        }
}

// ---------------------------------------------------------------------------
extern "C" void kernel_launch(void* const* d_in, const int* in_sizes, int n_in,
                              void* d_out, int out_size, void* d_ws, size_t ws_size,
                              hipStream_t stream)
{
    const float* x  = (const float*)d_in[0];
    const float* rc = (const float*)d_in[1];
    const float* rs = (const float*)d_in[2];
    const float* Wq = (const float*)d_in[3];
    const float* Wk = (const float*)d_in[4];
    const float* Wv = (const float*)d_in[5];
    const float* Wo = (const float*)d_in[6];
    float* out = (float*)d_out;

    ushort_t* xb   = (ushort_t*)d_ws;                          // 2048*1024
    ushort_t* WqT  = xb   + (size_t)2048 * 1024;               // 1024*1024
    ushort_t* WkT  = WqT  + (size_t)1024 * 1024;               //  256*1024
    ushort_t* WvT  = WkT  + (size_t)256 * 1024;                //  256*1024
    ushort_t* WoT  = WvT  + (size_t)256 * 1024;                // 1024*1024
    ushort_t* Qb   = WoT  + (size_t)1024 * 1024;               // 16*2048*64
    ushort_t* Kb   = Qb   + (size_t)NH * S_LEN * HD;           //  4*2048*64
    ushort_t* Vtb  = Kb   + (size_t)NKV * S_LEN * HD;          //  4*64*2048
    ushort_t* attnb= Vtb  + (size_t)NKV * HD * S_LEN;          // 2048*1024

    prep_kernel<<<dim3(16, 16, 5), 256, 0, stream>>>(x, xb, Wq, Wk, Wv, Wo,
                                                     WqT, WkT, WvT, WoT);
    gemm_qkv_mfma<<<dim3(32, 24), 256, 0, stream>>>(xb, WqT, WkT, WvT,
                                                    rc, rs, Qb, Kb, Vtb);
    attn_mfma<<<dim3(NH, 32), 256, 0, stream>>>(Qb, Kb, Vtb, attnb);
    gemm_out_mfma<<<dim3(32, 16), 256, 0, stream>>>(attnb, WoT, out);
}

// Round 8
// 140.738 us; speedup vs baseline: 1.0397x; 1.0397x over previous
//
#include <hip/hip_runtime.h>

typedef unsigned short ushort_t;
typedef __attribute__((ext_vector_type(8))) short short8;
typedef __attribute__((ext_vector_type(4))) float f32x4;
typedef __attribute__((ext_vector_type(4))) unsigned short ushort4v;
typedef __attribute__((ext_vector_type(8))) unsigned short ushort8v;

#define S_LEN 2048
#define D_MODEL 1024
#define NH 16
#define NKV 4
#define HD 64

// fp32 -> bf16 round-to-nearest-even
__device__ __forceinline__ ushort_t f2bf(float f) {
    unsigned u = __float_as_uint(f);
    u += 0x7fffu + ((u >> 16) & 1u);
    return (ushort_t)(u >> 16);
}

// async global->LDS, 16B/lane; LDS base wave-uniform, HW scatters lane*16
__device__ __forceinline__ void cp16(void* lds, const void* g) {
    __builtin_amdgcn_global_load_lds(
        (__attribute__((address_space(1))) void*)g,
        (__attribute__((address_space(3))) void*)lds, 16, 0, 0);
}

// ---------------------------------------------------------------------------
// Preprocess: z=0..3 -> weight transpose+cast W[k][n] fp32 -> WT[n][k] bf16;
// z=4 -> x fp32 -> bf16. grid (16,16,5).  (baseline verbatim)
// ---------------------------------------------------------------------------
__global__ __launch_bounds__(256) void prep_kernel(
    const float* __restrict__ x, ushort_t* __restrict__ xb,
    const float* __restrict__ Wq, const float* __restrict__ Wk,
    const float* __restrict__ Wv, const float* __restrict__ Wo,
    ushort_t* __restrict__ WqT, ushort_t* __restrict__ WkT,
    ushort_t* __restrict__ WvT, ushort_t* __restrict__ WoT)
{
    const int t = threadIdx.x;
    if (blockIdx.z == 4) {
        const int b  = blockIdx.y * 16 + blockIdx.x;
        const int i0 = (b * 256 + t) * 4;
        #pragma unroll
        for (int rep = 0; rep < 8; ++rep) {
            const int i = i0 + rep * 262144;   // 8 x 256K covers 2048*1024
            float4 v = *(const float4*)(x + i);
            ushort4v o = { f2bf(v.x), f2bf(v.y), f2bf(v.z), f2bf(v.w) };
            *(ushort4v*)(xb + i) = o;
        }
        return;
    }
    __shared__ ushort_t T[64 * 72];
    const float* W; ushort_t* WT; int N;
    switch (blockIdx.z) {
        case 0:  W = Wq; WT = WqT; N = 1024; break;
        case 1:  W = Wk; WT = WkT; N = 256;  break;
        case 2:  W = Wv; WT = WvT; N = 256;  break;
        default: W = Wo; WT = WoT; N = 1024; break;
    }
    const int n0 = blockIdx.y * 64;
    if (n0 >= N) return;
    const int k0 = blockIdx.x * 64;
    const int kr = t >> 4, nc = (t & 15) * 4;
    #pragma unroll
    for (int p = 0; p < 4; ++p) {
        const int k = kr + p * 16;
        float4 v = *(const float4*)(W + (size_t)(k0 + k) * N + n0 + nc);
        T[(nc + 0) * 72 + k] = f2bf(v.x);
        T[(nc + 1) * 72 + k] = f2bf(v.y);
        T[(nc + 2) * 72 + k] = f2bf(v.z);
        T[(nc + 3) * 72 + k] = f2bf(v.w);
    }
    __syncthreads();
    const int n = t >> 2, seg = (t & 3) * 16;
    ushort8v a = *(ushort8v*)&T[n * 72 + seg];
    ushort8v b = *(ushort8v*)&T[n * 72 + seg + 8];
    *(ushort8v*)(WT + (size_t)(n0 + n) * 1024 + k0 + seg)     = a;
    *(ushort8v*)(WT + (size_t)(n0 + n) * 1024 + k0 + seg + 8) = b;
}

// ---------------------------------------------------------------------------
// QKV projection (R6 structure kept): 64x64 tile, grid (32,24)=768 balanced,
// 4-deep circular LDS + counted vmcnt + raw s_barrier (T4).
// ---------------------------------------------------------------------------
__global__ __launch_bounds__(256, 2) void gemm_qkv_mfma(
    const ushort_t* __restrict__ xb, const ushort_t* __restrict__ WqT,
    const ushort_t* __restrict__ WkT, const ushort_t* __restrict__ WvT,
    const float* __restrict__ rc, const float* __restrict__ rs,
    ushort_t* __restrict__ Qb, ushort_t* __restrict__ Kb,
    ushort_t* __restrict__ Vtb)
{
    __shared__ ushort_t As[4][64 * 64];    // 32 KB
    __shared__ ushort_t Bs[4][64 * 64];    // 32 KB

    const int t = threadIdx.x;
    const int lane = t & 63, wave = t >> 6;
    const int wr = wave >> 1, wc = wave & 1;
    const int quad = lane >> 4, l15 = lane & 15;
    const int lq = lane >> 3, lr = lane & 7;
    const int swz_st = (lr ^ lq) * 8;
    const int l7 = l15 & 7;
    const int fsw0 = (quad ^ l7) * 8;
    const int fsw1 = ((quad + 4) ^ l7) * 8;

    const int m0 = blockIdx.x * 64;
    const int cy = blockIdx.y;

    const ushort_t* WT; int nloc;
    if (cy < 16)      { WT = WqT; nloc = cy * 64; }
    else if (cy < 20) { WT = WkT; nloc = (cy - 16) * 64; }
    else              { WT = WvT; nloc = (cy - 20) * 64; }

    f32x4 acc[2][2];
    #pragma unroll
    for (int i = 0; i < 2; ++i)
        #pragma unroll
        for (int j = 0; j < 2; ++j) acc[i][j] = (f32x4)0.f;

    auto stage = [&](int buf, int k0) {
        #pragma unroll
        for (int i = 0; i < 2; ++i) {
            const int r = wave * 16 + i * 8 + lq;
            cp16(&As[buf][(wave * 16 + i * 8) * 64],
                 xb + (size_t)(m0 + r) * 1024 + k0 + swz_st);
            cp16(&Bs[buf][(wave * 16 + i * 8) * 64],
                 WT + (size_t)(nloc + r) * 1024 + k0 + swz_st);
        }
    };

    auto compute = [&](int cur) {
        const ushort_t* Ac = &As[cur][0];
        const ushort_t* Bc = &Bs[cur][0];
        #pragma unroll
        for (int h = 0; h < 2; ++h) {
            const int fsw = h ? fsw1 : fsw0;
            short8 av[2], bv[2];
            #pragma unroll
            for (int i = 0; i < 2; ++i)
                av[i] = *(const short8*)&Ac[(wr * 32 + i * 16 + l15) * 64 + fsw];
            #pragma unroll
            for (int j = 0; j < 2; ++j)   // interleaved cols wc*16 + j*32
                bv[j] = *(const short8*)&Bc[(wc * 16 + j * 32 + l15) * 64 + fsw];
            #pragma unroll
            for (int i = 0; i < 2; ++i)
                #pragma unroll
                for (int j = 0; j < 2; ++j)
                    acc[i][j] = __builtin_amdgcn_mfma_f32_16x16x32_bf16(
                        av[i], bv[j], acc[i][j], 0, 0, 0);
        }
    };

    stage(0, 0);
    stage(1, 64);
    stage(2, 128);

    for (int kk = 0; kk < 14; ++kk) {
        asm volatile("s_waitcnt vmcnt(8)" ::: "memory");
        __builtin_amdgcn_s_barrier();
        __builtin_amdgcn_sched_barrier(0);
        if (kk < 13) stage((kk + 3) & 3, (kk + 3) * 64);
        compute(kk & 3);
    }
    asm volatile("s_waitcnt vmcnt(4)" ::: "memory");
    __builtin_amdgcn_s_barrier();
    __builtin_amdgcn_sched_barrier(0);
    compute(2);                      // 14 & 3
    asm volatile("s_waitcnt vmcnt(0)" ::: "memory");
    __builtin_amdgcn_s_barrier();
    __builtin_amdgcn_sched_barrier(0);
    compute(3);                      // 15 & 3

    // epilogue: C/D layout col = l15, row = quad*4+reg (+16i)  [m89]
    if (cy < 20) {
        ushort_t* dst = (cy < 16) ? Qb : Kb;
        const int h = (cy < 16) ? cy : (cy - 16);
        const int d = wc * 16 + l15;
        #pragma unroll
        for (int i = 0; i < 2; ++i) {
            #pragma unroll
            for (int reg = 0; reg < 4; ++reg) {
                const int s = m0 + wr * 32 + i * 16 + quad * 4 + reg;
                const float c  = rc[s * 32 + d];
                const float sn = rs[s * 32 + d];
                const float v1 = acc[i][0][reg];    // x[d]
                const float v2 = acc[i][1][reg];    // x[d+32]
                dst[((size_t)h * S_LEN + s) * HD + d]      = f2bf(v1 * c - v2 * sn);
                dst[((size_t)h * S_LEN + s) * HD + d + 32] = f2bf(v2 * c + v1 * sn);
            }
        }
    } else {
        const int vh = cy - 20;
        #pragma unroll
        for (int i = 0; i < 2; ++i) {
            const int s0 = m0 + wr * 32 + i * 16 + quad * 4;
            #pragma unroll
            for (int j = 0; j < 2; ++j) {
                const int d = wc * 16 + j * 32 + l15;
                ushort4v o = { f2bf(acc[i][j][0]), f2bf(acc[i][j][1]),
                               f2bf(acc[i][j][2]), f2bf(acc[i][j][3]) };
                *(ushort4v*)&Vtb[((size_t)vh * HD + d) * S_LEN + s0] = o;
            }
        }
    }
}

// ---------------------------------------------------------------------------
// MFMA flash attention, ROUND 8: baseline staging (128-KV dbuf rounds,
// __syncthreads) + 2x2 wave split of each 64x64 sub-tile: wave (qh,kvh)
// owns 32 q x 32 kv. K/V LDS reads per wave halve (4+4 b128 vs 8+8);
// block LDS cycles/sub-tile 992 -> 608. Fully-masked quadrant skipped.
// kv-half partial O / row-sums combined via fp32 LDS buffer (reuses Ks)
// after the final round barrier.
// ---------------------------------------------------------------------------
__global__ __launch_bounds__(256, 2) void attn_mfma(
    const ushort_t* __restrict__ Qb, const ushort_t* __restrict__ Kb,
    const ushort_t* __restrict__ Vtb, ushort_t* __restrict__ attnb)
{
    __shared__ ushort_t Ks[2][2][64 * 64];   // 32 KB [buf][sub][kv][d] swizzled
    __shared__ ushort_t Vs[2][2][64 * 64];   // 32 KB [buf][sub][d][kv] swizzled
    __shared__ ushort_t Ps[4][32 * 40];      // 10 KB wave-private P (stride 40)

    const int t = threadIdx.x;
    const int lane = t & 63, wave = t >> 6;
    const int quad = lane >> 4, l15 = lane & 15;
    const int lq = lane >> 3, lr = lane & 7;
    const int swz_st = (lr ^ lq) * 8;
    const int l7 = l15 & 7;

    const int qh  = wave >> 1;          // q half (32 rows)
    const int kvh = wave & 1;           // kv half (32 cols)
    const int kvL0 = kvh * 32;

    // swizzled read offsets: LDS[row][seg] holds global seg (seg ^ (row&7))
    const int fswK0 = (quad ^ l7) * 8;              // d-seg quad   (k 0..31)
    const int fswK1 = ((quad + 4) ^ l7) * 8;        // d-seg quad+4 (k 32..63)
    const int fswV  = (((kvh << 2) + quad) ^ l7) * 8; // kv-seg kvh*4+quad

    const int h  = blockIdx.x;
    const int y  = blockIdx.y;
    const int qt = (y < 16) ? y : 47 - y;
    const int q0 = qt * 64;
    const int kvhead = h >> 2;
    const int qrow0 = q0 + qh * 32;     // wave's first q row

    const ushort_t* Qg = Qb + ((size_t)h * S_LEN + qrow0) * HD;
    const ushort_t* Kg = Kb + (size_t)kvhead * S_LEN * HD;
    const ushort_t* Vg = Vtb + (size_t)kvhead * HD * S_LEN;

    // Q A-frags: [mq][kh]  (rows qrow0+mq*16+l15, k = kh*32+quad*8)
    short8 aq[2][2];
    #pragma unroll
    for (int mq = 0; mq < 2; ++mq)
        #pragma unroll
        for (int kh = 0; kh < 2; ++kh)
            aq[mq][kh] = *(const short8*)(Qg + (size_t)(mq * 16 + l15) * HD
                                          + kh * 32 + quad * 8);

    float ps[2][4];
    #pragma unroll
    for (int mq = 0; mq < 2; ++mq)
        #pragma unroll
        for (int r = 0; r < 4; ++r) ps[mq][r] = 0.f;
    f32x4 Oacc[2][4];
    #pragma unroll
    for (int mq = 0; mq < 2; ++mq)
        #pragma unroll
        for (int jb = 0; jb < 4; ++jb) Oacc[mq][jb] = (f32x4)0.f;

    const int nround = (qt + 2) >> 1;   // rounds of 128 KV cols

    auto stage = [&](int buf, int kvbase) {
        #pragma unroll
        for (int u = 0; u < 2; ++u)
            #pragma unroll
            for (int i = 0; i < 2; ++i) {
                const int r = wave * 16 + i * 8 + lq;
                cp16(&Ks[buf][u][(wave * 16 + i * 8) * 64],
                     Kg + (size_t)(kvbase + u * 64 + r) * 64 + swz_st);
                cp16(&Vs[buf][u][(wave * 16 + i * 8) * 64],
                     Vg + (size_t)r * 2048 + kvbase + u * 64 + swz_st);
            }
    };

    stage(0, 0);
    __syncthreads();

    ushort_t* Pw = &Ps[wave][0];

    for (int round = 0; round < nround; ++round) {
        const int cur = round & 1;
        if (round + 1 < nround) stage(cur ^ 1, (round + 1) * 128);

        #pragma unroll
        for (int u = 0; u < 2; ++u) {
            const int kv0 = round * 128 + u * 64;
            if (kv0 > q0 + 63) break;        // fully masked sub-tile (block)
            const bool diag = (kv0 == q0);
            // wave quadrant fully masked (diag, kv cols all > q rows)?
            if (diag && kvL0 > qh * 32 + 31) continue;
            const ushort_t* Kc = &Ks[cur][u][0];
            const ushort_t* Vc = &Vs[cur][u][0];

            // K B-frags for this wave's 32 kv rows
            short8 kb[2][2];
            #pragma unroll
            for (int jbl = 0; jbl < 2; ++jbl) {
                kb[jbl][0] = *(const short8*)&Kc[(kvL0 + jbl * 16 + l15) * 64 + fswK0];
                kb[jbl][1] = *(const short8*)&Kc[(kvL0 + jbl * 16 + l15) * 64 + fswK1];
            }

            // S = Q K^T  (2 mq x 2 jbl, K=64 via 2 chained mfma)
            f32x4 sv[2][2];
            #pragma unroll
            for (int mq = 0; mq < 2; ++mq)
                #pragma unroll
                for (int jbl = 0; jbl < 2; ++jbl) {
                    f32x4 z = (f32x4)0.f;
                    z = __builtin_amdgcn_mfma_f32_16x16x32_bf16(aq[mq][0], kb[jbl][0], z, 0, 0, 0);
                    z = __builtin_amdgcn_mfma_f32_16x16x32_bf16(aq[mq][1], kb[jbl][1], z, 0, 0, 0);
                    sv[mq][jbl] = z;
                }

            // max-free softmax: P = exp(s/8); elementwise mask on diag sub-tile
            #pragma unroll
            for (int mq = 0; mq < 2; ++mq)
                #pragma unroll
                for (int jbl = 0; jbl < 2; ++jbl) {
                    const int colg = kv0 + kvL0 + jbl * 16 + l15;
                    #pragma unroll
                    for (int reg = 0; reg < 4; ++reg) {
                        float e = __expf(sv[mq][jbl][reg] * 0.125f);
                        const int qg = qrow0 + mq * 16 + quad * 4 + reg;
                        if (diag && colg > qg) e = 0.f;
                        sv[mq][jbl][reg] = e;
                        ps[mq][reg] += e;
                    }
                }

            // P: C-layout -> wave-private LDS [32 q][40] -> A-layout frags
            #pragma unroll
            for (int mq = 0; mq < 2; ++mq)
                #pragma unroll
                for (int jbl = 0; jbl < 2; ++jbl)
                    #pragma unroll
                    for (int reg = 0; reg < 4; ++reg)
                        Pw[(mq * 16 + quad * 4 + reg) * 40 + jbl * 16 + l15] =
                            f2bf(sv[mq][jbl][reg]);
            short8 pa[2];
            #pragma unroll
            for (int mq = 0; mq < 2; ++mq)
                pa[mq] = *(const short8*)&Pw[(mq * 16 + l15) * 40 + quad * 8];

            // O += P V  (K=32 over wave's kv half)
            #pragma unroll
            for (int jb = 0; jb < 4; ++jb) {
                short8 vb = *(const short8*)&Vc[(jb * 16 + l15) * 64 + fswV];
                Oacc[0][jb] = __builtin_amdgcn_mfma_f32_16x16x32_bf16(pa[0], vb, Oacc[0][jb], 0, 0, 0);
                Oacc[1][jb] = __builtin_amdgcn_mfma_f32_16x16x32_bf16(pa[1], vb, Oacc[1][jb], 0, 0, 0);
            }
        }

        __syncthreads();   // drain stage(round+1), guard buffer reuse
    }

    // intra-wave row sums (reduce over l15 lanes)
    #pragma unroll
    for (int mq = 0; mq < 2; ++mq)
        #pragma unroll
        for (int reg = 0; reg < 4; ++reg) {
            float l = ps[mq][reg];
            l += __shfl_xor(l, 1);
            l += __shfl_xor(l, 2);
            l += __shfl_xor(l, 4);
            l += __shfl_xor(l, 8);
            ps[mq][reg] = l;
        }

    // cross-wave combine (kv halves) via fp32 buffer reused from Ks.
    // Layout: [qh][32 rows][68]; col 64 = row sum.  Safe after final barrier.
    float* Rbuf = (float*)&Ks[0][0][0];
    if (kvh == 1) {
        #pragma unroll
        for (int mq = 0; mq < 2; ++mq)
            #pragma unroll
            for (int reg = 0; reg < 4; ++reg) {
                const int row = mq * 16 + quad * 4 + reg;
                #pragma unroll
                for (int jb = 0; jb < 4; ++jb)
                    Rbuf[qh * 2176 + row * 68 + jb * 16 + l15] = Oacc[mq][jb][reg];
                if (l15 == 0)
                    Rbuf[qh * 2176 + row * 68 + 64] = ps[mq][reg];
            }
    }
    __syncthreads();
    if (kvh == 0) {
        #pragma unroll
        for (int mq = 0; mq < 2; ++mq)
            #pragma unroll
            for (int reg = 0; reg < 4; ++reg) {
                const int row = mq * 16 + quad * 4 + reg;
                const float ltot = ps[mq][reg] + Rbuf[qh * 2176 + row * 68 + 64];
                const float inv = 1.f / ltot;
                const int sq = qrow0 + row;
                #pragma unroll
                for (int jb = 0; jb < 4; ++jb) {
                    const float o = Oacc[mq][jb][reg]
                                  + Rbuf[qh * 2176 + row * 68 + jb * 16 + l15];
                    attnb[(size_t)sq * D_MODEL + h * HD + jb * 16 + l15] =
                        f2bf(o * inv);
                }
            }
    }
}

// ---------------------------------------------------------------------------
// Output projection (R6 structure kept): 64x64 tile, grid (32,16)=512,
// 4-deep circular LDS, counted vmcnt.
// ---------------------------------------------------------------------------
__global__ __launch_bounds__(256, 2) void gemm_out_mfma(
    const ushort_t* __restrict__ Ab, const ushort_t* __restrict__ WoT,
    float* __restrict__ out)
{
    __shared__ ushort_t As[4][64 * 64];    // 32 KB
    __shared__ ushort_t Bs[4][64 * 64];    // 32 KB

    const int t = threadIdx.x;
    const int lane = t & 63, wave = t >> 6;
    const int wr = wave >> 1, wc = wave & 1;
    const int quad = lane >> 4, l15 = lane & 15;
    const int lq = lane >> 3, lr = lane & 7;
    const int swz_st = (lr ^ lq) * 8;
    const int l7 = l15 & 7;
    const int fsw0 = (quad ^ l7) * 8;
    const int fsw1 = ((quad + 4) ^ l7) * 8;

    const int m0 = blockIdx.x * 64;
    const int n0 = blockIdx.y * 64;

    f32x4 acc[2][2];
    #pragma unroll
    for (int i = 0; i < 2; ++i)
        #pragma unroll
        for (int j = 0; j < 2; ++j) acc[i][j] = (f32x4)0.f;

    auto stage = [&](int buf, int k0) {
        #pragma unroll
        for (int i = 0; i < 2; ++i) {
            const int r = wave * 16 + i * 8 + lq;
            cp16(&As[buf][(wave * 16 + i * 8) * 64],
                 Ab + (size_t)(m0 + r) * 1024 + k0 + swz_st);
            cp16(&Bs[buf][(wave * 16 + i * 8) * 64],
                 WoT + (size_t)(n0 + r) * 1024 + k0 + swz_st);
        }
    };

    auto compute = [&](int cur) {
        const ushort_t* Ac = &As[cur][0];
        const ushort_t* Bc = &Bs[cur][0];
        #pragma unroll
        for (int h = 0; h < 2; ++h) {
            const int fsw = h ? fsw1 : fsw0;
            short8 av[2], bv[2];
            #pragma unroll
            for (int i = 0; i < 2; ++i)
                av[i] = *(const short8*)&Ac[(wr * 32 + i * 16 + l15) * 64 + fsw];
            #pragma unroll
            for (int j = 0; j < 2; ++j)
                bv[j] = *(const short8*)&Bc[(wc * 32 + j * 16 + l15) * 64 + fsw];
            #pragma unroll
            for (int i = 0; i < 2; ++i)
                #pragma unroll
                for (int j = 0; j < 2; ++j)
                    acc[i][j] = __builtin_amdgcn_mfma_f32_16x16x32_bf16(
                        av[i], bv[j], acc[i][j], 0, 0, 0);
        }
    };

    stage(0, 0);
    stage(1, 64);
    stage(2, 128);

    for (int kk = 0; kk < 14; ++kk) {
        asm volatile("s_waitcnt vmcnt(8)" ::: "memory");
        __builtin_amdgcn_s_barrier();
        __builtin_amdgcn_sched_barrier(0);
        if (kk < 13) stage((kk + 3) & 3, (kk + 3) * 64);
        compute(kk & 3);
    }
    asm volatile("s_waitcnt vmcnt(4)" ::: "memory");
    __builtin_amdgcn_s_barrier();
    __builtin_amdgcn_sched_barrier(0);
    compute(2);                      // 14 & 3
    asm volatile("s_waitcnt vmcnt(0)" ::: "memory");
    __builtin_amdgcn_s_barrier();
    __builtin_amdgcn_sched_barrier(0);
    compute(3);                      // 15 & 3

    #pragma unroll
    for (int i = 0; i < 2; ++i)
        #pragma unroll
        for (int reg = 0; reg < 4; ++reg) {
            const int s = m0 + wr * 32 + i * 16 + quad * 4 + reg;
            #pragma unroll
            for (int j = 0; j < 2; ++j)
                out[(size_t)s * D_MODEL + n0 + wc * 32 + j * 16 + l15] = acc[i][j][reg];
        }
}

// ---------------------------------------------------------------------------
extern "C" void kernel_launch(void* const* d_in, const int* in_sizes, int n_in,
                              void* d_out, int out_size, void* d_ws, size_t ws_size,
                              hipStream_t stream)
{
    const float* x  = (const float*)d_in[0];
    const float* rc = (const float*)d_in[1];
    const float* rs = (const float*)d_in[2];
    const float* Wq = (const float*)d_in[3];
    const float* Wk = (const float*)d_in[4];
    const float* Wv = (const float*)d_in[5];
    const float* Wo = (const float*)d_in[6];
    float* out = (float*)d_out;

    ushort_t* xb   = (ushort_t*)d_ws;                          // 2048*1024
    ushort_t* WqT  = xb   + (size_t)2048 * 1024;               // 1024*1024
    ushort_t* WkT  = WqT  + (size_t)1024 * 1024;               //  256*1024
    ushort_t* WvT  = WkT  + (size_t)256 * 1024;                //  256*1024
    ushort_t* WoT  = WvT  + (size_t)256 * 1024;                // 1024*1024
    ushort_t* Qb   = WoT  + (size_t)1024 * 1024;               // 16*2048*64
    ushort_t* Kb   = Qb   + (size_t)NH * S_LEN * HD;           //  4*2048*64
    ushort_t* Vtb  = Kb   + (size_t)NKV * S_LEN * HD;          //  4*64*2048
    ushort_t* attnb= Vtb  + (size_t)NKV * HD * S_LEN;          // 2048*1024

    prep_kernel<<<dim3(16, 16, 5), 256, 0, stream>>>(x, xb, Wq, Wk, Wv, Wo,
                                                     WqT, WkT, WvT, WoT);
    gemm_qkv_mfma<<<dim3(32, 24), 256, 0, stream>>>(xb, WqT, WkT, WvT,
                                                    rc, rs, Qb, Kb, Vtb);
    attn_mfma<<<dim3(NH, 32), 256, 0, stream>>>(Qb, Kb, Vtb, attnb);
    gemm_out_mfma<<<dim3(32, 16), 256, 0, stream>>>(attnb, WoT, out);
}